// Round 1
// baseline (227.991 us; speedup 1.0000x reference)
//
#include <hip/hip_runtime.h>

#define Hh 96
#define Ww 96
#define CIN 64
#define COUT 64
#define BATCH 8
#define HW 9216           // Hh*Ww
#define NOFF 18           // 2*K*K

// ---------------------------------------------------------------------------
// K1: offset conv (18 channels, 3x3, pad 1) + fold w_def transpose.
// Block = 256 threads = 4 waves; 64 pixels per block; each wave accumulates
// 16 input channels, then LDS reduction across waves.
// ---------------------------------------------------------------------------
__global__ __launch_bounds__(256) void k_offset(
    const float* __restrict__ x, const float* __restrict__ w_off,
    const float* __restrict__ b_off, const float* __restrict__ w_def,
    float* __restrict__ offs, float* __restrict__ wt)
{
  __shared__ float wl[CIN * 9 * 20];       // [c][kk][j padded to 20] = 46080 B
  __shared__ float red[3 * NOFF * 64];     // partial accs of waves 1..3

  int tid = threadIdx.x;
  int blk = blockIdx.x;

  // one-time transpose w_def[o][c][k] -> wt[k][c][o]  (36864 elements)
  if (blk < 144) {
    int g = blk * 256 + tid;
    int k = g >> 12, c = (g >> 6) & 63, o = g & 63;
    wt[g] = w_def[(o * 64 + c) * 9 + k];
  }

  // stage w_off into LDS: w_off flat index i = (j*64+c)*9+kk
  for (int i = tid; i < NOFF * CIN * 9; i += 256) {
    int j = i / 576;
    int rem = i - j * 576;
    int c = rem / 9;
    int kk = rem - c * 9;
    wl[(c * 9 + kk) * 20 + j] = w_off[i];
  }
  __syncthreads();

  int wave = tid >> 6, lane = tid & 63;
  int p = blk * 64 + lane;                 // global pixel id over B*HW
  int b = p / HW;
  int pp = p - b * HW;
  int h = pp / Ww;
  int w = pp - h * Ww;

  float acc[NOFF];
  #pragma unroll
  for (int j = 0; j < NOFF; ++j) acc[j] = 0.f;

  // precompute clamped window offsets + validity
  int woff[9];
  float okf[9];
  #pragma unroll
  for (int kk = 0; kk < 9; ++kk) {
    int yy = h + kk / 3 - 1, xx = w + (kk % 3) - 1;
    bool ok = (yy >= 0 && yy < Hh && xx >= 0 && xx < Ww);
    int yc = min(max(yy, 0), Hh - 1), xc = min(max(xx, 0), Ww - 1);
    woff[kk] = yc * Ww + xc;
    okf[kk] = ok ? 1.f : 0.f;
  }

  const float* xb = x + (size_t)(b * CIN + wave * 16) * HW;
  for (int ci = 0; ci < 16; ++ci) {
    const float* xc = xb + ci * HW;
    int c = wave * 16 + ci;
    float xv[9];
    #pragma unroll
    for (int kk = 0; kk < 9; ++kk) xv[kk] = xc[woff[kk]] * okf[kk];
    const float* wr = &wl[c * 180];
    #pragma unroll
    for (int kk = 0; kk < 9; ++kk) {
      const float* wj = wr + kk * 20;
      #pragma unroll
      for (int j = 0; j < NOFF; ++j)
        acc[j] = fmaf(xv[kk], wj[j], acc[j]);
    }
  }

  if (wave > 0) {
    #pragma unroll
    for (int j = 0; j < NOFF; ++j)
      red[(wave - 1) * NOFF * 64 + j * 64 + lane] = acc[j];
  }
  __syncthreads();
  if (wave == 0) {
    #pragma unroll
    for (int j = 0; j < NOFF; ++j) {
      float a = acc[j] + red[j * 64 + lane] + red[1152 + j * 64 + lane] +
                red[2304 + j * 64 + lane];
      offs[((size_t)b * NOFF + j) * HW + pp] = a + b_off[j];
    }
  }
}

// ---------------------------------------------------------------------------
// K2: deformable sampling + 576->64 contraction.
// Block = 256 threads, 64 pixels, all 64 output channels.
// Per k: build S[c][p] (bilinear samples) and Wk[c][o] in LDS, then 4x4
// register-blocked GEMM: acc[p][o] += S[c][p]*Wk[c][o].
// ---------------------------------------------------------------------------
__global__ __launch_bounds__(256) void k_deform(
    const float* __restrict__ x, const float* __restrict__ offs,
    const float* __restrict__ wt, const float* __restrict__ b_def,
    float* __restrict__ out)
{
  __shared__ float S[64 * 64];    // [c][p] 16 KB
  __shared__ float Wk[64 * 64];   // [c][o] 16 KB

  int tid = threadIdx.x;
  int blk = blockIdx.x;           // 1152 = 8 * 144
  int b = blk / 144;
  int pbase = (blk - b * 144) * 64;
  int wave = tid >> 6, lane = tid & 63;
  int p = pbase + lane;
  int h = p / Ww, w = p - h * Ww;
  int p0 = (tid & 15) * 4, o0 = (tid >> 4) * 4;

  float acc[4][4];
  #pragma unroll
  for (int i = 0; i < 4; ++i)
    #pragma unroll
    for (int j = 0; j < 4; ++j) acc[i][j] = 0.f;

  const float* xb = x + (size_t)(b * CIN + wave * 16) * HW;

  for (int k = 0; k < 9; ++k) {
    // stage Wk[c][o] (4096 floats) via float4
    {
      const float4* wtk = (const float4*)(wt + k * 4096);
      float4* Wk4 = (float4*)Wk;
      #pragma unroll
      for (int i = 0; i < 4; ++i) Wk4[tid + i * 256] = wtk[tid + i * 256];
    }

    // per-lane bilinear coords for this k
    float dy = offs[((size_t)b * NOFF + 2 * k) * HW + p];
    float dx = offs[((size_t)b * NOFF + 2 * k + 1) * HW + p];
    float py = (float)(h + k / 3 - 1) + dy;
    float px = (float)(w + (k % 3) - 1) + dx;
    float y0f = floorf(py), x0f = floorf(px);
    float ly = py - y0f, lx = px - x0f;
    int y0 = (int)y0f, x0 = (int)x0f;
    int y1 = y0 + 1, x1 = x0 + 1;
    float wy0 = 1.f - ly, wy1 = ly, wx0 = 1.f - lx, wx1 = lx;
    float fy0 = (y0 >= 0 && y0 < Hh) ? 1.f : 0.f;
    float fy1 = (y1 >= 0 && y1 < Hh) ? 1.f : 0.f;
    float fx0 = (x0 >= 0 && x0 < Ww) ? 1.f : 0.f;
    float fx1 = (x1 >= 0 && x1 < Ww) ? 1.f : 0.f;
    int cy0 = min(max(y0, 0), Hh - 1), cy1 = min(max(y1, 0), Hh - 1);
    int cx0 = min(max(x0, 0), Ww - 1), cx1 = min(max(x1, 0), Ww - 1);
    int o00 = cy0 * Ww + cx0, o01 = cy0 * Ww + cx1;
    int o10 = cy1 * Ww + cx0, o11 = cy1 * Ww + cx1;
    float w00 = (wy0 * wx0) * (fy0 * fx0);
    float w01 = (wy0 * wx1) * (fy0 * fx1);
    float w10 = (wy1 * wx0) * (fy1 * fx0);
    float w11 = (wy1 * wx1) * (fy1 * fx1);

    // build S: wave handles channels [wave*16, wave*16+16)
    #pragma unroll
    for (int ci = 0; ci < 16; ++ci) {
      const float* xc = xb + ci * HW;
      float v = w00 * xc[o00] + w01 * xc[o01] + w10 * xc[o10] + w11 * xc[o11];
      S[(wave * 16 + ci) * 64 + lane] = v;
    }
    __syncthreads();

    // 4x4 register-blocked contraction
    #pragma unroll 8
    for (int c = 0; c < 64; ++c) {
      float4 s4 = *(const float4*)&S[c * 64 + p0];
      float4 w4 = *(const float4*)&Wk[c * 64 + o0];
      acc[0][0] = fmaf(s4.x, w4.x, acc[0][0]);
      acc[0][1] = fmaf(s4.x, w4.y, acc[0][1]);
      acc[0][2] = fmaf(s4.x, w4.z, acc[0][2]);
      acc[0][3] = fmaf(s4.x, w4.w, acc[0][3]);
      acc[1][0] = fmaf(s4.y, w4.x, acc[1][0]);
      acc[1][1] = fmaf(s4.y, w4.y, acc[1][1]);
      acc[1][2] = fmaf(s4.y, w4.z, acc[1][2]);
      acc[1][3] = fmaf(s4.y, w4.w, acc[1][3]);
      acc[2][0] = fmaf(s4.z, w4.x, acc[2][0]);
      acc[2][1] = fmaf(s4.z, w4.y, acc[2][1]);
      acc[2][2] = fmaf(s4.z, w4.z, acc[2][2]);
      acc[2][3] = fmaf(s4.z, w4.w, acc[2][3]);
      acc[3][0] = fmaf(s4.w, w4.x, acc[3][0]);
      acc[3][1] = fmaf(s4.w, w4.y, acc[3][1]);
      acc[3][2] = fmaf(s4.w, w4.z, acc[3][2]);
      acc[3][3] = fmaf(s4.w, w4.w, acc[3][3]);
    }
    __syncthreads();
  }

  // epilogue: add bias, write pre-BN output
  #pragma unroll
  for (int j = 0; j < 4; ++j) {
    float bo = b_def[o0 + j];
    float4 r;
    r.x = acc[0][j] + bo;
    r.y = acc[1][j] + bo;
    r.z = acc[2][j] + bo;
    r.w = acc[3][j] + bo;
    *(float4*)&out[((size_t)b * COUT + o0 + j) * HW + pbase + p0] = r;
  }
}

// ---------------------------------------------------------------------------
// K3a: per-(b,c) partial sum/sumsq.  512 blocks.
// ---------------------------------------------------------------------------
__global__ __launch_bounds__(256) void k_stats_a(
    const float* __restrict__ out, float* __restrict__ parts)
{
  int c = blockIdx.x & 63;
  int b = blockIdx.x >> 6;
  int tid = threadIdx.x;
  const float* pl = out + ((size_t)b * COUT + c) * HW;
  float s = 0.f, ss = 0.f;
  for (int i = tid; i < HW; i += 256) {
    float v = pl[i];
    s += v;
    ss = fmaf(v, v, ss);
  }
  #pragma unroll
  for (int off = 32; off >= 1; off >>= 1) {
    s += __shfl_down(s, off);
    ss += __shfl_down(ss, off);
  }
  __shared__ float rs[4], rss[4];
  int wave = tid >> 6, lane = tid & 63;
  if (lane == 0) { rs[wave] = s; rss[wave] = ss; }
  __syncthreads();
  if (tid == 0) {
    parts[blockIdx.x] = rs[0] + rs[1] + rs[2] + rs[3];
    parts[512 + blockIdx.x] = rss[0] + rss[1] + rss[2] + rss[3];
  }
}

// ---------------------------------------------------------------------------
// K3b: finalize BN scale/shift per channel.  1 block, 64 threads.
// ---------------------------------------------------------------------------
__global__ void k_stats_b(
    const float* __restrict__ parts, const float* __restrict__ gamma,
    const float* __restrict__ beta, float* __restrict__ stats)
{
  int c = threadIdx.x;
  float s = 0.f, ss = 0.f;
  #pragma unroll
  for (int b = 0; b < 8; ++b) {
    s += parts[b * 64 + c];
    ss += parts[512 + b * 64 + c];
  }
  const float inv = 1.f / 73728.f;
  float mean = s * inv;
  float var = ss * inv - mean * mean;
  float scale = gamma[c] * rsqrtf(var + 1e-5f);
  stats[c] = scale;
  stats[64 + c] = beta[c] - mean * scale;
}

// ---------------------------------------------------------------------------
// K4: in-place normalize + affine + relu, float4 vectorized.
// ---------------------------------------------------------------------------
__global__ __launch_bounds__(256) void k_norm(
    float* __restrict__ out, const float* __restrict__ stats)
{
  int g = blockIdx.x * 256 + threadIdx.x;   // over 1179648 float4
  int o = (g / 2304) & 63;                  // 2304 float4 per plane
  float sc = stats[o], sh = stats[64 + o];
  float4 v = ((const float4*)out)[g];
  v.x = fmaxf(fmaf(v.x, sc, sh), 0.f);
  v.y = fmaxf(fmaf(v.y, sc, sh), 0.f);
  v.z = fmaxf(fmaf(v.z, sc, sh), 0.f);
  v.w = fmaxf(fmaf(v.w, sc, sh), 0.f);
  ((float4*)out)[g] = v;
}

extern "C" void kernel_launch(void* const* d_in, const int* in_sizes, int n_in,
                              void* d_out, int out_size, void* d_ws, size_t ws_size,
                              hipStream_t stream) {
  const float* x     = (const float*)d_in[0];
  const float* w_off = (const float*)d_in[1];
  const float* b_off = (const float*)d_in[2];
  const float* w_def = (const float*)d_in[3];
  const float* b_def = (const float*)d_in[4];
  const float* gamma = (const float*)d_in[5];
  const float* beta  = (const float*)d_in[6];
  float* out = (float*)d_out;

  float* offs  = (float*)d_ws;            // 8*18*9216 = 1327104 floats
  float* wt    = offs + 1327104;          // 36864 floats
  float* stats = wt + 36864;              // 128 floats
  float* parts = stats + 128;             // 1024 floats

  k_offset<<<1152, 256, 0, stream>>>(x, w_off, b_off, w_def, offs, wt);
  k_deform<<<1152, 256, 0, stream>>>(x, offs, wt, b_def, out);
  k_stats_a<<<512, 256, 0, stream>>>(out, parts);
  k_stats_b<<<1, 64, 0, stream>>>(parts, gamma, beta, stats);
  k_norm<<<4608, 256, 0, stream>>>(out, stats);
}